// Round 5
// baseline (360.895 us; speedup 1.0000x reference)
//
#include <hip/hip_runtime.h>
#include <hip/hip_bf16.h>
#include <cstddef>

typedef __attribute__((ext_vector_type(8))) short short8;
typedef __attribute__((ext_vector_type(16))) float float16;

#define C_CH 192
#define PK   9408      // C_CH * 49
#define D1   768

__device__ __forceinline__ ushort f2bf(float v) {
    return __builtin_bit_cast(unsigned short, __float2bfloat16(v));
}
__device__ __forceinline__ float bf2f(ushort u) {
    return __builtin_bit_cast(float, ((unsigned int)u) << 16);
}

// ---------------------------------------------------------------------------
// fp32 -> bf16 conversion (vectorized float4 -> 4x bf16)
// ---------------------------------------------------------------------------
__global__ __launch_bounds__(256) void cvt_bf16(const float* __restrict__ in,
                                                ushort* __restrict__ out, int n4)
{
    int i = blockIdx.x * 256 + threadIdx.x;
    if (i >= n4) return;
    float4 v = ((const float4*)in)[i];
    ushort4 o;
    o.x = f2bf(v.x); o.y = f2bf(v.y); o.z = f2bf(v.z); o.w = f2bf(v.w);
    ((ushort4*)out)[i] = o;
}

// ---------------------------------------------------------------------------
// All 4 pyramid levels NCHW(fp32) -> NHWC(bf16), one launch.
// grid.x: 680 tiles (lvl0 512, lvl1 128, lvl2 32, lvl3 8), grid.y = batch.
// ---------------------------------------------------------------------------
__global__ __launch_bounds__(256) void nchw_to_nhwc(
    const float* __restrict__ f0, const float* __restrict__ f1,
    const float* __restrict__ f2, const float* __restrict__ f3,
    ushort* __restrict__ o0, ushort* __restrict__ o1,
    ushort* __restrict__ o2, ushort* __restrict__ o3)
{
    __shared__ float sm[C_CH][33];
    int t = blockIdx.x;
    int b = blockIdx.y;
    const float* in; ushort* out; int HW, hw0;
    if      (t < 512) { in = f0; out = o0; HW = 16384; hw0 = t * 32; }
    else if (t < 640) { in = f1; out = o1; HW = 4096;  hw0 = (t - 512) * 32; }
    else if (t < 672) { in = f2; out = o2; HW = 1024;  hw0 = (t - 640) * 32; }
    else              { in = f3; out = o3; HW = 256;   hw0 = (t - 672) * 32; }

    int tx = threadIdx.x & 31;
    int ty = threadIdx.x >> 5;    // 0..7

    const float* ip = in + (size_t)b * C_CH * HW + hw0;
    #pragma unroll
    for (int c = 0; c < C_CH; c += 8)
        sm[c + ty][tx] = ip[(size_t)(c + ty) * HW + tx];
    __syncthreads();

    ushort* op = out + ((size_t)b * HW + hw0) * C_CH;
    #pragma unroll
    for (int r0 = 0; r0 < 32; r0 += 8) {
        int r = r0 + ty;
        #pragma unroll
        for (int cc = 0; cc < 6; ++cc) {
            int c = cc * 32 + tx;
            op[(size_t)r * C_CH + c] = f2bf(sm[c][r]);
        }
    }
}

// ---------------------------------------------------------------------------
// RoIAlign gather from NHWC bf16: one block per RoI, 384 threads =
// (bin-half 0/1) x (192 channels). Tap offsets made wave-uniform via
// readfirstlane -> scalar base + vector channel offset.
// filter >= 0: only process RoIs whose pyramid level == filter.
// ---------------------------------------------------------------------------
__global__ __launch_bounds__(384) void roi_gather(
    const ushort* __restrict__ n0p, const ushort* __restrict__ n1p,
    const ushort* __restrict__ n2p, const ushort* __restrict__ n3p,
    const float* __restrict__ rois, ushort* __restrict__ pooled, int filter)
{
    __shared__ int   s_off[196][4];
    __shared__ float s_w[196][4];
    __shared__ ushort s_out[PK];

    const int n   = blockIdx.x;
    const int tid = threadIdx.x;

    float by1 = rois[n*5+0], bx1 = rois[n*5+1];
    float by2 = rois[n*5+2], bx2 = rois[n*5+3];
    int   b   = (int)rois[n*5+4];

    float hh = by2 - by1, ww = bx2 - bx1;
    int lvl = (int)rintf(4.0f + log2f(sqrtf(hh * ww)));
    lvl = min(max(lvl, 0), 3);
    if (filter >= 0 && lvl != filter) return;   // uniform across block

    const ushort* fm; int H;
    if      (lvl == 0) { fm = n0p; H = 128; }
    else if (lvl == 1) { fm = n1p; H = 64;  }
    else if (lvl == 2) { fm = n2p; H = 32;  }
    else               { fm = n3p; H = 16;  }
    float Hf = (float)H;

    float y1p = by1 * Hf, x1p = bx1 * Hf;
    float y2p = by2 * Hf, x2p = bx2 * Hf;
    float bin_h = fmaxf(y2p - y1p, 1.0f) * (1.0f / 7.0f);
    float bin_w = fmaxf(x2p - x1p, 1.0f) * (1.0f / 7.0f);

    const ushort* base = fm + (size_t)b * H * H * C_CH;

    if (tid < 196) {
        int s  = tid;
        int sx = s & 1, sy = (s >> 1) & 1, ij = s >> 2;
        int i = ij / 7, j = ij - i * 7;

        float gy = (float)i + 0.25f + 0.5f * (float)sy;
        float y  = y1p + gy * bin_h;
        bool  vy = (y >= -1.0f) && (y <= Hf);
        float yc = fminf(fmaxf(y, 0.0f), Hf - 1.0f);
        int   y0 = (int)floorf(yc);
        float ly = yc - (float)y0;
        int   y1i = min(y0 + 1, H - 1);

        float gx = (float)j + 0.25f + 0.5f * (float)sx;
        float x  = x1p + gx * bin_w;
        bool  vx = (x >= -1.0f) && (x <= Hf);
        float xc = fminf(fmaxf(x, 0.0f), Hf - 1.0f);
        int   x0 = (int)floorf(xc);
        float lx = xc - (float)x0;
        int   x1i = min(x0 + 1, H - 1);

        float vm = (vy && vx) ? 0.25f : 0.0f;
        s_off[s][0] = (y0  * H + x0 ) * C_CH;
        s_off[s][1] = (y0  * H + x1i) * C_CH;
        s_off[s][2] = (y1i * H + x0 ) * C_CH;
        s_off[s][3] = (y1i * H + x1i) * C_CH;
        s_w[s][0] = (1.0f - ly) * (1.0f - lx) * vm;
        s_w[s][1] = (1.0f - ly) * lx * vm;
        s_w[s][2] = ly * (1.0f - lx) * vm;
        s_w[s][3] = ly * lx * vm;
    }
    __syncthreads();

    const int half = tid / C_CH;        // 0 or 1 (waves don't straddle: 192=3*64)
    const int c    = tid - half * C_CH; // channel
    const int bin_lo = half * 25;
    const int bin_hi = min(bin_lo + 25, 49);

    for (int bin = bin_lo; bin < bin_hi; ++bin) {
        float acc = 0.0f;
        #pragma unroll
        for (int sub = 0; sub < 4; ++sub) {
            int s = bin * 4 + sub;
            #pragma unroll
            for (int tp = 0; tp < 4; ++tp) {
                int off = __builtin_amdgcn_readfirstlane(s_off[s][tp]);
                float w = s_w[s][tp];
                acc = fmaf(bf2f(base[off + c]), w, acc);
            }
        }
        s_out[c * 49 + bin] = f2bf(acc);
    }
    __syncthreads();

    unsigned int* po = (unsigned int*)(pooled + (size_t)n * PK);
    const unsigned int* so = (const unsigned int*)s_out;
    for (int idx = tid; idx < PK / 2; idx += 384) po[idx] = so[idx];
}

// ---------------------------------------------------------------------------
// RoIAlign from NCHW fp32 (fallback path, proven): 1 thread / output element
// ---------------------------------------------------------------------------
__global__ __launch_bounds__(256) void roi_align_nchw(
    const float* __restrict__ f0, const float* __restrict__ f1,
    const float* __restrict__ f2, const float* __restrict__ f3,
    const float* __restrict__ rois, ushort* __restrict__ pooled, int n_rois)
{
    int idx = blockIdx.x * 256 + threadIdx.x;
    if (idx >= n_rois * PK) return;
    int n  = idx / PK;
    int r  = idx - n * PK;
    int c  = r / 49;
    int ij = r - c * 49;
    int i  = ij / 7;
    int j  = ij - i * 7;

    float by1 = rois[n*5+0], bx1 = rois[n*5+1];
    float by2 = rois[n*5+2], bx2 = rois[n*5+3];
    int   b   = (int)rois[n*5+4];

    float hh = by2 - by1, ww = bx2 - bx1;
    int lvl = (int)rintf(4.0f + log2f(sqrtf(hh * ww)));
    lvl = min(max(lvl, 0), 3);

    const float* fmap; int H;
    if      (lvl == 0) { fmap = f0; H = 128; }
    else if (lvl == 1) { fmap = f1; H = 64;  }
    else if (lvl == 2) { fmap = f2; H = 32;  }
    else               { fmap = f3; H = 16;  }
    float Hf = (float)H;

    float y1p = by1 * Hf, x1p = bx1 * Hf;
    float bin_h = fmaxf(by2 * Hf - y1p, 1.0f) * (1.0f / 7.0f);
    float bin_w = fmaxf(bx2 * Hf - x1p, 1.0f) * (1.0f / 7.0f);

    const float* base = fmap + ((size_t)b * C_CH + c) * (size_t)(H * H);

    float acc = 0.0f;
    #pragma unroll
    for (int sy = 0; sy < 2; ++sy) {
        float y  = y1p + ((float)i + 0.25f + 0.5f * (float)sy) * bin_h;
        bool  vy = (y >= -1.0f) && (y <= Hf);
        float yc = fminf(fmaxf(y, 0.0f), Hf - 1.0f);
        int   y0 = (int)floorf(yc);
        float ly = yc - (float)y0;
        int   y1i = min(y0 + 1, H - 1);
        #pragma unroll
        for (int sx = 0; sx < 2; ++sx) {
            float x  = x1p + ((float)j + 0.25f + 0.5f * (float)sx) * bin_w;
            bool  vx = (x >= -1.0f) && (x <= Hf);
            float xc = fminf(fmaxf(x, 0.0f), Hf - 1.0f);
            int   x0 = (int)floorf(xc);
            float lx = xc - (float)x0;
            int   x1i = min(x0 + 1, H - 1);
            if (vy && vx) {
                float v = base[y0 * H + x0 ] * (1.0f - ly) * (1.0f - lx)
                        + base[y0 * H + x1i] * (1.0f - ly) * lx
                        + base[y1i * H + x0 ] * ly * (1.0f - lx)
                        + base[y1i * H + x1i] * ly * lx;
                acc += v;
            }
        }
    }
    pooled[idx] = f2bf(acc * 0.25f);
}

// ---------------------------------------------------------------------------
// bf16 MFMA GEMM, 64x64 tile (used for FC2 / fallback paths).
// MODE 0: fp32 out, bias+relu.  MODE 1: bf16 out, bias+relu.
// MODE 2: fp32 partial (no bias), out += blockIdx.z*M*N, kb = z*nkIters.
// ---------------------------------------------------------------------------
template<int MODE>
__global__ __launch_bounds__(256) void mfma_gemm(
    const ushort* __restrict__ A, const ushort* __restrict__ W,
    const float* __restrict__ bias, void* __restrict__ outp,
    int M, int N, int K, int nkIters)
{
    __shared__ char ldsA[2][8192];
    __shared__ char ldsB[2][8192];

    const int t    = threadIdx.x;
    const int lane = t & 63;
    const int wave = t >> 6;
    const int wm = wave >> 1, wn = wave & 1;

    const int m0 = blockIdx.y * 64;
    const int n0 = blockIdx.x * 64;
    const int kb = (MODE == 2) ? blockIdx.z * nkIters : 0;

    const int ks   = t & 3;
    const int mrow = t >> 2;
    const int g    = mrow >> 5;
    const int rw   = mrow & 31;
    const int lof0 = ks*2048 + g*1024 + ((     rw) ^ (ks<<2))*16;
    const int lof1 = ks*2048 + g*1024 + ((32 + rw) ^ (ks<<2))*16;

    const int arow = min(m0 + mrow, M-1);
    const int brow = n0 + mrow;
    const ushort* ap = A + (size_t)arow * K + (size_t)kb * 64 + ks*16;
    const ushort* bp = W + (size_t)brow * K + (size_t)kb * 64 + ks*16;

    const int nk = nkIters;

    float4 ra0, ra1, rb0, rb1;
    float4 qa0, qa1, qb0, qb1;

    ra0 = ((const float4*)ap)[0]; ra1 = ((const float4*)ap)[1];
    rb0 = ((const float4*)bp)[0]; rb1 = ((const float4*)bp)[1];
    *(float4*)&ldsA[0][lof0] = ra0; *(float4*)&ldsA[0][lof1] = ra1;
    *(float4*)&ldsB[0][lof0] = rb0; *(float4*)&ldsB[0][lof1] = rb1;
    {
        int k1 = min(1, nk - 1);
        const ushort* ap1 = ap + (size_t)k1 * 64;
        const ushort* bp1 = bp + (size_t)k1 * 64;
        ra0 = ((const float4*)ap1)[0]; ra1 = ((const float4*)ap1)[1];
        rb0 = ((const float4*)bp1)[0]; rb1 = ((const float4*)bp1)[1];
    }
    __syncthreads();

    float16 acc = {};

    for (int kt = 0; kt < nk; ++kt) {
        {
            int k2 = min(kt + 2, nk - 1);
            const ushort* ap2 = ap + (size_t)k2 * 64;
            const ushort* bp2 = bp + (size_t)k2 * 64;
            qa0 = ((const float4*)ap2)[0]; qa1 = ((const float4*)ap2)[1];
            qb0 = ((const float4*)bp2)[0]; qb1 = ((const float4*)bp2)[1];
        }
        if (kt + 1 < nk) {
            char* dA = ldsA[(kt+1)&1]; char* dB = ldsB[(kt+1)&1];
            *(float4*)&dA[lof0] = ra0; *(float4*)&dA[lof1] = ra1;
            *(float4*)&dB[lof0] = rb0; *(float4*)&dB[lof1] = rb1;
        }
        const char* sA = ldsA[kt&1]; const char* sB = ldsB[kt&1];
        #pragma unroll
        for (int s = 0; s < 4; ++s) {
            int ro = s*2048 + (lane ^ (s<<2))*16;
            short8 af = *(const short8*)&sA[wm*1024 + ro];
            short8 bf = *(const short8*)&sB[wn*1024 + ro];
            acc = __builtin_amdgcn_mfma_f32_32x32x16_bf16(af, bf, acc, 0, 0, 0);
        }
        __syncthreads();
        ra0 = qa0; ra1 = qa1; rb0 = qb0; rb1 = qb1;
    }

    const int col   = lane & 31;
    const int rbase = 4 * (lane >> 5);
    const int nG    = n0 + wn*32 + col;

    if (MODE == 2) {
        float* O = (float*)outp + (size_t)blockIdx.z * M * N;
        #pragma unroll
        for (int r = 0; r < 16; ++r) {
            int row = (r & 3) + 8*(r >> 2) + rbase;
            int mG  = m0 + wm*32 + row;
            if (mG < M) O[(size_t)mG * N + nG] = acc[r];
        }
    } else if (MODE == 1) {
        const float bv = bias[nG];
        ushort* O = (ushort*)outp;
        #pragma unroll
        for (int r = 0; r < 16; ++r) {
            int row = (r & 3) + 8*(r >> 2) + rbase;
            int mG  = m0 + wm*32 + row;
            if (mG < M) O[(size_t)mG * N + nG] = f2bf(fmaxf(acc[r] + bv, 0.0f));
        }
    } else {
        const float bv = bias[nG];
        float* O = (float*)outp;
        #pragma unroll
        for (int r = 0; r < 16; ++r) {
            int row = (r & 3) + 8*(r >> 2) + rbase;
            int mG  = m0 + wm*32 + row;
            if (mG < M) O[(size_t)mG * N + nG] = fmaxf(acc[r] + bv, 0.0f);
        }
    }
}

// ---------------------------------------------------------------------------
// bf16 MFMA GEMM, 128x128 tile, BK=64, split-K partials (ragged).
// 4 waves, each computing a 64x64 quadrant as 2x2 of 32x32 mfma.
// LDS: per matrix per buffer 16KB = 4 ks * 4 rowgroups * 64 slots * 16B,
// slot = (h*32 + row32) ^ (ks<<2)  -> conflict-free b128 both directions.
// Total LDS 64KB (2 matrices x double buffer).
// ---------------------------------------------------------------------------
__global__ __launch_bounds__(256) void mfma_gemm128(
    const ushort* __restrict__ A, const ushort* __restrict__ W,
    float* __restrict__ P, int M, int N, int K, int nkPer, int nkTotal)
{
    __shared__ char ldsA[2][16384];
    __shared__ char ldsB[2][16384];

    const int t    = threadIdx.x;
    const int lane = t & 63;
    const int wave = t >> 6;
    const int wm = wave >> 1, wn = wave & 1;

    const int m0 = blockIdx.y * 128;
    const int n0 = blockIdx.x * 128;
    const int kb = blockIdx.z * nkPer;
    const int nk = min(nkPer, nkTotal - kb);

    const int ks   = t & 3;           // k-subtile 0..3
    const int mrow = t >> 2;          // 0..63 (rows mrow and mrow+64)
    const int g    = mrow >> 5;       // 0..1 (rowgroups 2,3 are +64 rows)
    const int rw   = mrow & 31;
    const int swz  = ks << 2;
    const int lo_h0 = ks*4096 + g*1024 + ((     rw) ^ swz)*16;
    const int lo_h1 = ks*4096 + g*1024 + ((32 + rw) ^ swz)*16;
    // row mrow+64 -> rowgroup g+2 -> +2048 bytes

    const int ar0 = min(m0 + mrow,      M-1);
    const int ar1 = min(m0 + mrow + 64, M-1);
    const ushort* ap0 = A + (size_t)ar0 * K + (size_t)kb * 64 + ks*16;
    const ushort* ap1 = A + (size_t)ar1 * K + (size_t)kb * 64 + ks*16;
    const ushort* bp0 = W + (size_t)(n0 + mrow)      * K + (size_t)kb * 64 + ks*16;
    const ushort* bp1 = W + (size_t)(n0 + mrow + 64) * K + (size_t)kb * 64 + ks*16;

    float4 ra[4], rb[4], qa[4], qb[4];

    ra[0] = ((const float4*)ap0)[0]; ra[1] = ((const float4*)ap0)[1];
    ra[2] = ((const float4*)ap1)[0]; ra[3] = ((const float4*)ap1)[1];
    rb[0] = ((const float4*)bp0)[0]; rb[1] = ((const float4*)bp0)[1];
    rb[2] = ((const float4*)bp1)[0]; rb[3] = ((const float4*)bp1)[1];
    *(float4*)&ldsA[0][lo_h0       ] = ra[0]; *(float4*)&ldsA[0][lo_h1       ] = ra[1];
    *(float4*)&ldsA[0][lo_h0 + 2048] = ra[2]; *(float4*)&ldsA[0][lo_h1 + 2048] = ra[3];
    *(float4*)&ldsB[0][lo_h0       ] = rb[0]; *(float4*)&ldsB[0][lo_h1       ] = rb[1];
    *(float4*)&ldsB[0][lo_h0 + 2048] = rb[2]; *(float4*)&ldsB[0][lo_h1 + 2048] = rb[3];
    {
        int k1 = min(1, nk - 1);
        size_t o = (size_t)k1 * 64;
        ra[0] = ((const float4*)(ap0 + o))[0]; ra[1] = ((const float4*)(ap0 + o))[1];
        ra[2] = ((const float4*)(ap1 + o))[0]; ra[3] = ((const float4*)(ap1 + o))[1];
        rb[0] = ((const float4*)(bp0 + o))[0]; rb[1] = ((const float4*)(bp0 + o))[1];
        rb[2] = ((const float4*)(bp1 + o))[0]; rb[3] = ((const float4*)(bp1 + o))[1];
    }
    __syncthreads();

    float16 zero = {};
    float16 acc00 = zero, acc01 = zero, acc10 = zero, acc11 = zero;

    for (int kt = 0; kt < nk; ++kt) {
        {
            int k2 = min(kt + 2, nk - 1);
            size_t o = (size_t)k2 * 64;
            qa[0] = ((const float4*)(ap0 + o))[0]; qa[1] = ((const float4*)(ap0 + o))[1];
            qa[2] = ((const float4*)(ap1 + o))[0]; qa[3] = ((const float4*)(ap1 + o))[1];
            qb[0] = ((const float4*)(bp0 + o))[0]; qb[1] = ((const float4*)(bp0 + o))[1];
            qb[2] = ((const float4*)(bp1 + o))[0]; qb[3] = ((const float4*)(bp1 + o))[1];
        }
        if (kt + 1 < nk) {
            char* dA = ldsA[(kt+1)&1]; char* dB = ldsB[(kt+1)&1];
            *(float4*)&dA[lo_h0       ] = ra[0]; *(float4*)&dA[lo_h1       ] = ra[1];
            *(float4*)&dA[lo_h0 + 2048] = ra[2]; *(float4*)&dA[lo_h1 + 2048] = ra[3];
            *(float4*)&dB[lo_h0       ] = rb[0]; *(float4*)&dB[lo_h1       ] = rb[1];
            *(float4*)&dB[lo_h0 + 2048] = rb[2]; *(float4*)&dB[lo_h1 + 2048] = rb[3];
        }
        const char* sA = ldsA[kt&1]; const char* sB = ldsB[kt&1];
        #pragma unroll
        for (int s = 0; s < 4; ++s) {
            int ro = (lane ^ (s<<2))*16 + s*4096;
            short8 a0 = *(const short8*)&sA[(wm*2 + 0)*1024 + ro];
            short8 a1 = *(const short8*)&sA[(wm*2 + 1)*1024 + ro];
            short8 b0 = *(const short8*)&sB[(wn*2 + 0)*1024 + ro];
            short8 b1 = *(const short8*)&sB[(wn*2 + 1)*1024 + ro];
            acc00 = __builtin_amdgcn_mfma_f32_32x32x16_bf16(a0, b0, acc00, 0, 0, 0);
            acc01 = __builtin_amdgcn_mfma_f32_32x32x16_bf16(a0, b1, acc01, 0, 0, 0);
            acc10 = __builtin_amdgcn_mfma_f32_32x32x16_bf16(a1, b0, acc10, 0, 0, 0);
            acc11 = __builtin_amdgcn_mfma_f32_32x32x16_bf16(a1, b1, acc11, 0, 0, 0);
        }
        __syncthreads();
        #pragma unroll
        for (int q = 0; q < 4; ++q) { ra[q] = qa[q]; rb[q] = qb[q]; }
    }

    // epilogue: partials, C/D map col=lane&31, row=(r&3)+8*(r>>2)+4*(lane>>5)
    float* O = P + (size_t)blockIdx.z * M * N;
    const int col   = lane & 31;
    const int rbase = 4 * (lane >> 5);
    #pragma unroll
    for (int ti = 0; ti < 2; ++ti) {
        const float16& aL = ti ? acc10 : acc00;
        const float16& aR = ti ? acc11 : acc01;
        #pragma unroll
        for (int r = 0; r < 16; ++r) {
            int row = (r & 3) + 8*(r >> 2) + rbase;
            int mG  = m0 + wm*64 + ti*32 + row;
            if (mG < M) {
                int nGL = n0 + wn*64 + col;
                O[(size_t)mG * N + nGL]      = aL[r];
                O[(size_t)mG * N + nGL + 32] = aR[r];
            }
        }
    }
}

// ---------------------------------------------------------------------------
// Split-K reduce: Y[m][n] = bf16(relu(bias[n] + sum_s P[s][m][n]))
// ---------------------------------------------------------------------------
__global__ __launch_bounds__(256) void reduce_relu_bf16(
    const float* __restrict__ P, const float* __restrict__ bias,
    ushort* __restrict__ Y, int MN, int N, int S)
{
    int idx = blockIdx.x * 256 + threadIdx.x;
    if (idx >= MN / 4) return;
    float4 s = ((const float4*)P)[idx];
    for (int k = 1; k < S; ++k) {
        float4 p = ((const float4*)(P + (size_t)k * MN))[idx];
        s.x += p.x; s.y += p.y; s.z += p.z; s.w += p.w;
    }
    int n4 = idx % (N / 4);
    float4 bv = ((const float4*)bias)[n4];
    ushort4 o;
    o.x = f2bf(fmaxf(s.x + bv.x, 0.0f));
    o.y = f2bf(fmaxf(s.y + bv.y, 0.0f));
    o.z = f2bf(fmaxf(s.z + bv.z, 0.0f));
    o.w = f2bf(fmaxf(s.w + bv.w, 0.0f));
    ((ushort4*)Y)[idx] = o;
}

// ---------------------------------------------------------------------------
// Heads: 14 outputs per RoI, K=768 fp32 dot each
// ---------------------------------------------------------------------------
__global__ __launch_bounds__(256) void heads_kernel(
    const float* __restrict__ Z,
    const float* __restrict__ w_bbox, const float* __restrict__ b_bbox,
    const float* __restrict__ w_cls,  const float* __restrict__ b_cls,
    const float* __restrict__ w_reg,  const float* __restrict__ b_reg,
    const float* __restrict__ w_unc,  const float* __restrict__ b_unc,
    float* __restrict__ out, int n_rois)
{
    int idx = blockIdx.x * 256 + threadIdx.x;
    if (idx >= n_rois * 14) return;
    int n = idx / 14;
    int o = idx - n * 14;

    const float* w; float bb;
    if      (o < 8)  { w = w_bbox + o * D1;        bb = b_bbox[o]; }
    else if (o < 10) { w = w_cls  + (o - 8) * D1;  bb = b_cls[o - 8]; }
    else if (o < 12) { w = w_reg  + (o - 10) * D1; bb = b_reg[o - 10]; }
    else             { w = w_unc  + (o - 12) * D1; bb = b_unc[o - 12]; }

    const float* z = Z + (size_t)n * D1;
    float s = bb;
    for (int k = 0; k < D1; k += 4) {
        float4 zv = *(const float4*)(z + k);
        float4 wv = *(const float4*)(w + k);
        s = fmaf(zv.x, wv.x, s);
        s = fmaf(zv.y, wv.y, s);
        s = fmaf(zv.z, wv.z, s);
        s = fmaf(zv.w, wv.w, s);
    }

    int off;
    int clsOff = n_rois * 8;
    int regOff = n_rois * 8 + n_rois * 2;
    if      (o < 8)  off = n * 8 + o;
    else if (o < 10) off = clsOff + n * 2 + (o - 8);
    else if (o < 12) off = regOff + n * 4 + (o - 10) * 2;
    else             off = regOff + n * 4 + (o - 12) * 2 + 1;
    out[off] = s;
}

// ---------------------------------------------------------------------------
extern "C" void kernel_launch(void* const* d_in, const int* in_sizes, int n_in,
                              void* d_out, int out_size, void* d_ws, size_t ws_size,
                              hipStream_t stream)
{
    const float* f0   = (const float*)d_in[0];
    const float* f1   = (const float*)d_in[1];
    const float* f2   = (const float*)d_in[2];
    const float* f3   = (const float*)d_in[3];
    const float* rois = (const float*)d_in[4];
    const float* w1   = (const float*)d_in[5];
    const float* b1   = (const float*)d_in[6];
    const float* w2   = (const float*)d_in[7];
    const float* b2   = (const float*)d_in[8];
    const float* w_bbox = (const float*)d_in[9];
    const float* b_bbox = (const float*)d_in[10];
    const float* w_cls  = (const float*)d_in[11];
    const float* b_cls  = (const float*)d_in[12];
    const float* w_reg  = (const float*)d_in[13];
    const float* b_reg  = (const float*)d_in[14];
    const float* w_unc  = (const float*)d_in[15];
    const float* b_unc  = (const float*)d_in[16];
    float* out = (float*)d_out;

    const int n_rois = in_sizes[4] / 5;                  // 1000
    const int B      = in_sizes[0] / (C_CH * 128 * 128); // 4

    const size_t nh0B = (size_t)B * 16384 * C_CH * 2;
    const size_t nh1B = (size_t)B * 4096  * C_CH * 2;
    const size_t nh2B = (size_t)B * 1024  * C_CH * 2;
    const size_t nh3B = (size_t)B * 256   * C_CH * 2;
    const size_t nhAll = nh0B + nh1B + nh2B + nh3B;      // 33.4 MB
    const size_t poolB = (size_t)n_rois * PK * 2;        // 18.8 MB
    const size_t w1Bb  = (size_t)D1 * PK * 2;            // 14.45 MB
    const size_t w2Bb  = (size_t)D1 * D1 * 2;
    const size_t Yb    = (size_t)n_rois * D1 * 2;
    const size_t Zb    = (size_t)n_rois * D1 * 4;
    const size_t smallB = w2Bb + Yb + Zb;

    const size_t needX = nhAll + poolB + smallB;         // ~58.0 MB (proven)
    const size_t needY = nh0B  + poolB + smallB;         // ~49.8 MB

    char* ws = (char*)d_ws;

    if (ws_size >= needX) {
        // ---------------- Plan X: all NHWC levels resident ----------------
        const int SPLITX = 5;       // ragged: 30,30,30,30,27 of 147 BK-iters
        // after gather, nhwc region (33.4 MB) is dead:
        //   w1B (14.45) + P (SPLITX*3.07=15.36) = 29.8 MB <= 33.4 ✓
        ushort* nh0 = (ushort*)ws;
        ushort* nh1 = nh0 + nh0B/2;
        ushort* nh2 = nh1 + nh1B/2;
        ushort* nh3 = nh2 + nh2B/2;
        ushort* w1B = (ushort*)ws;
        float*  P   = (float*)(ws + w1Bb);
        ushort* pooledB = (ushort*)(ws + nhAll);
        ushort* w2B = (ushort*)(ws + nhAll + poolB);
        ushort* Y   = w2B + w2Bb/2;
        float*  Z   = (float*)((char*)Y + Yb);

        nchw_to_nhwc<<<dim3(680, B), 256, 0, stream>>>(f0, f1, f2, f3,
                                                       nh0, nh1, nh2, nh3);
        roi_gather<<<n_rois, 384, 0, stream>>>(nh0, nh1, nh2, nh3, rois, pooledB, -1);

        cvt_bf16<<<((D1*PK/4) + 255)/256, 256, 0, stream>>>(w1, w1B, D1*PK/4);
        cvt_bf16<<<((D1*D1/4) + 255)/256, 256, 0, stream>>>(w2, w2B, D1*D1/4);

        {
            int nkTotal = PK / 64;                 // 147
            int nkPer   = (nkTotal + SPLITX - 1) / SPLITX;   // 30
            dim3 grid(D1/128, (n_rois + 127)/128, SPLITX);
            mfma_gemm128<<<grid, 256, 0, stream>>>(pooledB, w1B, P,
                                                   n_rois, D1, PK, nkPer, nkTotal);
            int MN = n_rois * D1;
            reduce_relu_bf16<<<(MN/4 + 255)/256, 256, 0, stream>>>(P, b1, Y, MN, D1, SPLITX);
        }
        {
            dim3 grid(D1/64, (n_rois + 63)/64, 1);
            mfma_gemm<0><<<grid, 256, 0, stream>>>(Y, w2B, b2, Z, n_rois, D1, D1, D1/64);
        }
        heads_kernel<<<(n_rois*14 + 255)/256, 256, 0, stream>>>(
            Z, w_bbox, b_bbox, w_cls, b_cls, w_reg, b_reg, w_unc, b_unc, out, n_rois);
    } else if (ws_size >= needY) {
        // ---------------- Plan Y: one staging region, per-level -----------
        const int SPLIT = 3;        // P (9.2 MB) + w1B (14.45) <= nh0B (25.2) ✓
        ushort* nh0 = (ushort*)ws;
        ushort* w1B = (ushort*)ws;
        float*  P   = (float*)(ws + w1Bb);
        ushort* pooledB = (ushort*)(ws + nh0B);
        ushort* w2B = (ushort*)(ws + nh0B + poolB);
        ushort* Y   = w2B + w2Bb/2;
        float*  Z   = (float*)((char*)Y + Yb);

        const float* fs[4] = {f0, f1, f2, f3};
        const int    hws[4] = {16384, 4096, 1024, 256};
        for (int l = 0; l < 4; ++l) {
            // reuse single-level repack via nchw_to_nhwc is not possible; use
            // per-level grid on the merged kernel's logic: emulate with roi path
            // (simplest proven): repack level l into nh0
            // (launch merged kernel with only that level's tiles is complex;
            //  use a dedicated small loop: reuse cvt-style is wrong layout.)
            // -> fall back to per-level repack below.
            (void)fs; (void)hws;
        }
        // per-level repack + filtered gather
        {
            // level 0
            nchw_to_nhwc<<<dim3(512, B), 256, 0, stream>>>(f0, f0, f0, f0, nh0, nh0, nh0, nh0);
            roi_gather<<<n_rois, 384, 0, stream>>>(nh0, nh0, nh0, nh0, rois, pooledB, 0);
            // level 1: tiles 512..639 -> shift: launch with f1 as "f0" using 128 tiles
            nchw_to_nhwc<<<dim3(128, B), 256, 0, stream>>>(f1, f1, f1, f1, nh0, nh0, nh0, nh0);
            roi_gather<<<n_rois, 384, 0, stream>>>(nh0, nh0, nh0, nh0, rois, pooledB, 1);
            nchw_to_nhwc<<<dim3(32, B), 256, 0, stream>>>(f2, f2, f2, f2, nh0, nh0, nh0, nh0);
            roi_gather<<<n_rois, 384, 0, stream>>>(nh0, nh0, nh0, nh0, rois, pooledB, 2);
            nchw_to_nhwc<<<dim3(8, B), 256, 0, stream>>>(f3, f3, f3, f3, nh0, nh0, nh0, nh0);
            roi_gather<<<n_rois, 384, 0, stream>>>(nh0, nh0, nh0, nh0, rois, pooledB, 3);
        }
        cvt_bf16<<<((D1*PK/4) + 255)/256, 256, 0, stream>>>(w1, w1B, D1*PK/4);
        cvt_bf16<<<((D1*D1/4) + 255)/256, 256, 0, stream>>>(w2, w2B, D1*D1/4);
        {
            dim3 grid(D1/64, (n_rois + 63)/64, SPLIT);
            mfma_gemm<2><<<grid, 256, 0, stream>>>(pooledB, w1B, nullptr, P,
                                                   n_rois, D1, PK, (PK/64)/SPLIT);
            int MN = n_rois * D1;
            reduce_relu_bf16<<<(MN/4 + 255)/256, 256, 0, stream>>>(P, b1, Y, MN, D1, SPLIT);
        }
        {
            dim3 grid(D1/64, (n_rois + 63)/64, 1);
            mfma_gemm<0><<<grid, 256, 0, stream>>>(Y, w2B, b2, Z, n_rois, D1, D1, D1/64);
        }
        heads_kernel<<<(n_rois*14 + 255)/256, 256, 0, stream>>>(
            Z, w_bbox, b_bbox, w_cls, b_cls, w_reg, b_reg, w_unc, b_unc, out, n_rois);
    } else {
        // ------- fallback: proven 39.1 MB layout (round-2 path) -------
        ushort* pooledB = (ushort*)ws;
        ushort* w1B = pooledB + poolB/2;
        ushort* w2B = w1B + w1Bb/2;
        ushort* Y   = w2B + w2Bb/2;
        float*  Z   = (float*)((char*)Y + Yb);

        cvt_bf16<<<((D1*PK/4) + 255)/256, 256, 0, stream>>>(w1, w1B, D1*PK/4);
        cvt_bf16<<<((D1*D1/4) + 255)/256, 256, 0, stream>>>(w2, w2B, D1*D1/4);
        {
            int total = n_rois * PK;
            roi_align_nchw<<<(total + 255)/256, 256, 0, stream>>>(
                f0, f1, f2, f3, rois, pooledB, n_rois);
        }
        {
            dim3 grid(D1/64, (n_rois + 63)/64);
            mfma_gemm<1><<<grid, 256, 0, stream>>>(pooledB, w1B, b1, Y, n_rois, D1, PK, PK/64);
        }
        {
            dim3 grid(D1/64, (n_rois + 63)/64);
            mfma_gemm<0><<<grid, 256, 0, stream>>>(Y, w2B, b2, Z, n_rois, D1, D1, D1/64);
        }
        heads_kernel<<<(n_rois*14 + 255)/256, 256, 0, stream>>>(
            Z, w_bbox, b_bbox, w_cls, b_cls, w_reg, b_reg, w_unc, b_unc, out, n_rois);
    }
}

// Round 6
// 274.406 us; speedup vs baseline: 1.3152x; 1.3152x over previous
//
#include <hip/hip_runtime.h>
#include <hip/hip_bf16.h>
#include <cstddef>

typedef __attribute__((ext_vector_type(8))) short short8;
typedef __attribute__((ext_vector_type(16))) float float16;

#define C_CH 192
#define PK   9408      // C_CH * 49
#define D1   768

__device__ __forceinline__ ushort f2bf(float v) {
    return __builtin_bit_cast(unsigned short, __float2bfloat16(v));
}
__device__ __forceinline__ float bf2f(ushort u) {
    return __builtin_bit_cast(float, ((unsigned int)u) << 16);
}

// ---------------------------------------------------------------------------
// fp32 -> bf16 conversion (vectorized float4 -> 4x bf16)
// ---------------------------------------------------------------------------
__global__ __launch_bounds__(256) void cvt_bf16(const float* __restrict__ in,
                                                ushort* __restrict__ out, int n4)
{
    int i = blockIdx.x * 256 + threadIdx.x;
    if (i >= n4) return;
    float4 v = ((const float4*)in)[i];
    ushort4 o;
    o.x = f2bf(v.x); o.y = f2bf(v.y); o.z = f2bf(v.z); o.w = f2bf(v.w);
    ((ushort4*)out)[i] = o;
}

// ---------------------------------------------------------------------------
// All 4 pyramid levels NCHW(fp32) -> NHWC(bf16), one launch.
// grid.x: 680 tiles (lvl0 512, lvl1 128, lvl2 32, lvl3 8), grid.y = batch.
// ---------------------------------------------------------------------------
__global__ __launch_bounds__(256) void nchw_to_nhwc(
    const float* __restrict__ f0, const float* __restrict__ f1,
    const float* __restrict__ f2, const float* __restrict__ f3,
    ushort* __restrict__ o0, ushort* __restrict__ o1,
    ushort* __restrict__ o2, ushort* __restrict__ o3)
{
    __shared__ float sm[C_CH][33];
    int t = blockIdx.x;
    int b = blockIdx.y;
    const float* in; ushort* out; int HW, hw0;
    if      (t < 512) { in = f0; out = o0; HW = 16384; hw0 = t * 32; }
    else if (t < 640) { in = f1; out = o1; HW = 4096;  hw0 = (t - 512) * 32; }
    else if (t < 672) { in = f2; out = o2; HW = 1024;  hw0 = (t - 640) * 32; }
    else              { in = f3; out = o3; HW = 256;   hw0 = (t - 672) * 32; }

    int tx = threadIdx.x & 31;
    int ty = threadIdx.x >> 5;    // 0..7

    const float* ip = in + (size_t)b * C_CH * HW + hw0;
    #pragma unroll
    for (int c = 0; c < C_CH; c += 8)
        sm[c + ty][tx] = ip[(size_t)(c + ty) * HW + tx];
    __syncthreads();

    ushort* op = out + ((size_t)b * HW + hw0) * C_CH;
    #pragma unroll
    for (int r0 = 0; r0 < 32; r0 += 8) {
        int r = r0 + ty;
        #pragma unroll
        for (int cc = 0; cc < 6; ++cc) {
            int c = cc * 32 + tx;
            op[(size_t)r * C_CH + c] = f2bf(sm[c][r]);
        }
    }
}

// ---------------------------------------------------------------------------
// RoIAlign gather from NHWC bf16: one block per RoI, 384 threads =
// (bin-half 0/1) x (192 channels). Tap offsets wave-uniform via readfirstlane.
// ---------------------------------------------------------------------------
__global__ __launch_bounds__(384) void roi_gather(
    const ushort* __restrict__ n0p, const ushort* __restrict__ n1p,
    const ushort* __restrict__ n2p, const ushort* __restrict__ n3p,
    const float* __restrict__ rois, ushort* __restrict__ pooled)
{
    __shared__ int   s_off[196][4];
    __shared__ float s_w[196][4];
    __shared__ ushort s_out[PK];

    const int n   = blockIdx.x;
    const int tid = threadIdx.x;

    float by1 = rois[n*5+0], bx1 = rois[n*5+1];
    float by2 = rois[n*5+2], bx2 = rois[n*5+3];
    int   b   = (int)rois[n*5+4];

    float hh = by2 - by1, ww = bx2 - bx1;
    int lvl = (int)rintf(4.0f + log2f(sqrtf(hh * ww)));
    lvl = min(max(lvl, 0), 3);

    const ushort* fm; int H;
    if      (lvl == 0) { fm = n0p; H = 128; }
    else if (lvl == 1) { fm = n1p; H = 64;  }
    else if (lvl == 2) { fm = n2p; H = 32;  }
    else               { fm = n3p; H = 16;  }
    float Hf = (float)H;

    float y1p = by1 * Hf, x1p = bx1 * Hf;
    float y2p = by2 * Hf, x2p = bx2 * Hf;
    float bin_h = fmaxf(y2p - y1p, 1.0f) * (1.0f / 7.0f);
    float bin_w = fmaxf(x2p - x1p, 1.0f) * (1.0f / 7.0f);

    const ushort* base = fm + (size_t)b * H * H * C_CH;

    if (tid < 196) {
        int s  = tid;
        int sx = s & 1, sy = (s >> 1) & 1, ij = s >> 2;
        int i = ij / 7, j = ij - i * 7;

        float gy = (float)i + 0.25f + 0.5f * (float)sy;
        float y  = y1p + gy * bin_h;
        bool  vy = (y >= -1.0f) && (y <= Hf);
        float yc = fminf(fmaxf(y, 0.0f), Hf - 1.0f);
        int   y0 = (int)floorf(yc);
        float ly = yc - (float)y0;
        int   y1i = min(y0 + 1, H - 1);

        float gx = (float)j + 0.25f + 0.5f * (float)sx;
        float x  = x1p + gx * bin_w;
        bool  vx = (x >= -1.0f) && (x <= Hf);
        float xc = fminf(fmaxf(x, 0.0f), Hf - 1.0f);
        int   x0 = (int)floorf(xc);
        float lx = xc - (float)x0;
        int   x1i = min(x0 + 1, H - 1);

        float vm = (vy && vx) ? 0.25f : 0.0f;
        s_off[s][0] = (y0  * H + x0 ) * C_CH;
        s_off[s][1] = (y0  * H + x1i) * C_CH;
        s_off[s][2] = (y1i * H + x0 ) * C_CH;
        s_off[s][3] = (y1i * H + x1i) * C_CH;
        s_w[s][0] = (1.0f - ly) * (1.0f - lx) * vm;
        s_w[s][1] = (1.0f - ly) * lx * vm;
        s_w[s][2] = ly * (1.0f - lx) * vm;
        s_w[s][3] = ly * lx * vm;
    }
    __syncthreads();

    const int half = tid / C_CH;        // 0 or 1 (waves don't straddle: 192=3*64)
    const int c    = tid - half * C_CH; // channel
    const int bin_lo = half * 25;
    const int bin_hi = min(bin_lo + 25, 49);

    for (int bin = bin_lo; bin < bin_hi; ++bin) {
        float acc = 0.0f;
        #pragma unroll
        for (int sub = 0; sub < 4; ++sub) {
            int s = bin * 4 + sub;
            #pragma unroll
            for (int tp = 0; tp < 4; ++tp) {
                int off = __builtin_amdgcn_readfirstlane(s_off[s][tp]);
                float w = s_w[s][tp];
                acc = fmaf(bf2f(base[off + c]), w, acc);
            }
        }
        s_out[c * 49 + bin] = f2bf(acc);
    }
    __syncthreads();

    unsigned int* po = (unsigned int*)(pooled + (size_t)n * PK);
    const unsigned int* so = (const unsigned int*)s_out;
    for (int idx = tid; idx < PK / 2; idx += 384) po[idx] = so[idx];
}

// ---------------------------------------------------------------------------
// RoIAlign from NCHW fp32 (fallback path, proven): 1 thread / output element
// ---------------------------------------------------------------------------
__global__ __launch_bounds__(256) void roi_align_nchw(
    const float* __restrict__ f0, const float* __restrict__ f1,
    const float* __restrict__ f2, const float* __restrict__ f3,
    const float* __restrict__ rois, ushort* __restrict__ pooled, int n_rois)
{
    int idx = blockIdx.x * 256 + threadIdx.x;
    if (idx >= n_rois * PK) return;
    int n  = idx / PK;
    int r  = idx - n * PK;
    int c  = r / 49;
    int ij = r - c * 49;
    int i  = ij / 7;
    int j  = ij - i * 7;

    float by1 = rois[n*5+0], bx1 = rois[n*5+1];
    float by2 = rois[n*5+2], bx2 = rois[n*5+3];
    int   b   = (int)rois[n*5+4];

    float hh = by2 - by1, ww = bx2 - bx1;
    int lvl = (int)rintf(4.0f + log2f(sqrtf(hh * ww)));
    lvl = min(max(lvl, 0), 3);

    const float* fmap; int H;
    if      (lvl == 0) { fmap = f0; H = 128; }
    else if (lvl == 1) { fmap = f1; H = 64;  }
    else if (lvl == 2) { fmap = f2; H = 32;  }
    else               { fmap = f3; H = 16;  }
    float Hf = (float)H;

    float y1p = by1 * Hf, x1p = bx1 * Hf;
    float bin_h = fmaxf(by2 * Hf - y1p, 1.0f) * (1.0f / 7.0f);
    float bin_w = fmaxf(bx2 * Hf - x1p, 1.0f) * (1.0f / 7.0f);

    const float* base = fmap + ((size_t)b * C_CH + c) * (size_t)(H * H);

    float acc = 0.0f;
    #pragma unroll
    for (int sy = 0; sy < 2; ++sy) {
        float y  = y1p + ((float)i + 0.25f + 0.5f * (float)sy) * bin_h;
        bool  vy = (y >= -1.0f) && (y <= Hf);
        float yc = fminf(fmaxf(y, 0.0f), Hf - 1.0f);
        int   y0 = (int)floorf(yc);
        float ly = yc - (float)y0;
        int   y1i = min(y0 + 1, H - 1);
        #pragma unroll
        for (int sx = 0; sx < 2; ++sx) {
            float x  = x1p + ((float)j + 0.25f + 0.5f * (float)sx) * bin_w;
            bool  vx = (x >= -1.0f) && (x <= Hf);
            float xc = fminf(fmaxf(x, 0.0f), Hf - 1.0f);
            int   x0 = (int)floorf(xc);
            float lx = xc - (float)x0;
            int   x1i = min(x0 + 1, H - 1);
            if (vy && vx) {
                float v = base[y0 * H + x0 ] * (1.0f - ly) * (1.0f - lx)
                        + base[y0 * H + x1i] * (1.0f - ly) * lx
                        + base[y1i * H + x0 ] * ly * (1.0f - lx)
                        + base[y1i * H + x1i] * ly * lx;
                acc += v;
            }
        }
    }
    pooled[idx] = f2bf(acc * 0.25f);
}

// ---------------------------------------------------------------------------
// bf16 MFMA GEMM, 64x64 tile, BK=64, 4 waves of 32x32 mfma, depth-2 register
// prefetch + double-buffered LDS, XOR-swizzled conflict-free layout.
// MODE 0: fp32 out, bias+relu.  MODE 1: bf16 out, bias+relu.
// MODE 2: fp32 partial (no bias), out += blockIdx.z*M*N,
//         k-blocks [blockIdx.z*nkPer, +min(nkPer, nkTotal - kb)) (ragged).
// ---------------------------------------------------------------------------
template<int MODE>
__global__ __launch_bounds__(256) void mfma_gemm(
    const ushort* __restrict__ A, const ushort* __restrict__ W,
    const float* __restrict__ bias, void* __restrict__ outp,
    int M, int N, int K, int nkPer, int nkTotal)
{
    __shared__ char ldsA[2][8192];
    __shared__ char ldsB[2][8192];

    const int t    = threadIdx.x;
    const int lane = t & 63;
    const int wave = t >> 6;
    const int wm = wave >> 1, wn = wave & 1;

    const int m0 = blockIdx.y * 64;
    const int n0 = blockIdx.x * 64;
    const int kb = (MODE == 2) ? blockIdx.z * nkPer : 0;
    const int nk = (MODE == 2) ? min(nkPer, nkTotal - kb) : nkPer;

    const int ks   = t & 3;
    const int mrow = t >> 2;
    const int g    = mrow >> 5;
    const int rw   = mrow & 31;
    const int lof0 = ks*2048 + g*1024 + ((     rw) ^ (ks<<2))*16;
    const int lof1 = ks*2048 + g*1024 + ((32 + rw) ^ (ks<<2))*16;

    const int arow = min(m0 + mrow, M-1);
    const int brow = n0 + mrow;
    const ushort* ap = A + (size_t)arow * K + (size_t)kb * 64 + ks*16;
    const ushort* bp = W + (size_t)brow * K + (size_t)kb * 64 + ks*16;

    float4 ra0, ra1, rb0, rb1;
    float4 qa0, qa1, qb0, qb1;

    ra0 = ((const float4*)ap)[0]; ra1 = ((const float4*)ap)[1];
    rb0 = ((const float4*)bp)[0]; rb1 = ((const float4*)bp)[1];
    *(float4*)&ldsA[0][lof0] = ra0; *(float4*)&ldsA[0][lof1] = ra1;
    *(float4*)&ldsB[0][lof0] = rb0; *(float4*)&ldsB[0][lof1] = rb1;
    {
        int k1 = min(1, nk - 1);
        const ushort* ap1 = ap + (size_t)k1 * 64;
        const ushort* bp1 = bp + (size_t)k1 * 64;
        ra0 = ((const float4*)ap1)[0]; ra1 = ((const float4*)ap1)[1];
        rb0 = ((const float4*)bp1)[0]; rb1 = ((const float4*)bp1)[1];
    }
    __syncthreads();

    float16 acc = {};

    for (int kt = 0; kt < nk; ++kt) {
        {
            int k2 = min(kt + 2, nk - 1);
            const ushort* ap2 = ap + (size_t)k2 * 64;
            const ushort* bp2 = bp + (size_t)k2 * 64;
            qa0 = ((const float4*)ap2)[0]; qa1 = ((const float4*)ap2)[1];
            qb0 = ((const float4*)bp2)[0]; qb1 = ((const float4*)bp2)[1];
        }
        if (kt + 1 < nk) {
            char* dA = ldsA[(kt+1)&1]; char* dB = ldsB[(kt+1)&1];
            *(float4*)&dA[lof0] = ra0; *(float4*)&dA[lof1] = ra1;
            *(float4*)&dB[lof0] = rb0; *(float4*)&dB[lof1] = rb1;
        }
        const char* sA = ldsA[kt&1]; const char* sB = ldsB[kt&1];
        #pragma unroll
        for (int s = 0; s < 4; ++s) {
            int ro = s*2048 + (lane ^ (s<<2))*16;
            short8 af = *(const short8*)&sA[wm*1024 + ro];
            short8 bf = *(const short8*)&sB[wn*1024 + ro];
            acc = __builtin_amdgcn_mfma_f32_32x32x16_bf16(af, bf, acc, 0, 0, 0);
        }
        __syncthreads();
        ra0 = qa0; ra1 = qa1; rb0 = qb0; rb1 = qb1;
    }

    const int col   = lane & 31;
    const int rbase = 4 * (lane >> 5);
    const int nG    = n0 + wn*32 + col;

    if (MODE == 2) {
        float* O = (float*)outp + (size_t)blockIdx.z * M * N;
        #pragma unroll
        for (int r = 0; r < 16; ++r) {
            int row = (r & 3) + 8*(r >> 2) + rbase;
            int mG  = m0 + wm*32 + row;
            if (mG < M) O[(size_t)mG * N + nG] = acc[r];
        }
    } else if (MODE == 1) {
        const float bv = bias[nG];
        ushort* O = (ushort*)outp;
        #pragma unroll
        for (int r = 0; r < 16; ++r) {
            int row = (r & 3) + 8*(r >> 2) + rbase;
            int mG  = m0 + wm*32 + row;
            if (mG < M) O[(size_t)mG * N + nG] = f2bf(fmaxf(acc[r] + bv, 0.0f));
        }
    } else {
        const float bv = bias[nG];
        float* O = (float*)outp;
        #pragma unroll
        for (int r = 0; r < 16; ++r) {
            int row = (r & 3) + 8*(r >> 2) + rbase;
            int mG  = m0 + wm*32 + row;
            if (mG < M) O[(size_t)mG * N + nG] = fmaxf(acc[r] + bv, 0.0f);
        }
    }
}

// ---------------------------------------------------------------------------
// Split-K reduces: bf16 out (FC1) and fp32 out (FC2)
// ---------------------------------------------------------------------------
__global__ __launch_bounds__(256) void reduce_relu_bf16(
    const float* __restrict__ P, const float* __restrict__ bias,
    ushort* __restrict__ Y, int MN, int N, int S)
{
    int idx = blockIdx.x * 256 + threadIdx.x;
    if (idx >= MN / 4) return;
    float4 s = ((const float4*)P)[idx];
    for (int k = 1; k < S; ++k) {
        float4 p = ((const float4*)(P + (size_t)k * MN))[idx];
        s.x += p.x; s.y += p.y; s.z += p.z; s.w += p.w;
    }
    int n4 = idx % (N / 4);
    float4 bv = ((const float4*)bias)[n4];
    ushort4 o;
    o.x = f2bf(fmaxf(s.x + bv.x, 0.0f));
    o.y = f2bf(fmaxf(s.y + bv.y, 0.0f));
    o.z = f2bf(fmaxf(s.z + bv.z, 0.0f));
    o.w = f2bf(fmaxf(s.w + bv.w, 0.0f));
    ((ushort4*)Y)[idx] = o;
}

__global__ __launch_bounds__(256) void reduce_relu_f32(
    const float* __restrict__ P, const float* __restrict__ bias,
    float* __restrict__ Z, int MN, int N, int S)
{
    int idx = blockIdx.x * 256 + threadIdx.x;
    if (idx >= MN / 4) return;
    float4 s = ((const float4*)P)[idx];
    for (int k = 1; k < S; ++k) {
        float4 p = ((const float4*)(P + (size_t)k * MN))[idx];
        s.x += p.x; s.y += p.y; s.z += p.z; s.w += p.w;
    }
    int n4 = idx % (N / 4);
    float4 bv = ((const float4*)bias)[n4];
    float4 o;
    o.x = fmaxf(s.x + bv.x, 0.0f);
    o.y = fmaxf(s.y + bv.y, 0.0f);
    o.z = fmaxf(s.z + bv.z, 0.0f);
    o.w = fmaxf(s.w + bv.w, 0.0f);
    ((float4*)Z)[idx] = o;
}

// ---------------------------------------------------------------------------
// Heads: 14 outputs per RoI, K=768 fp32 dot each
// ---------------------------------------------------------------------------
__global__ __launch_bounds__(256) void heads_kernel(
    const float* __restrict__ Z,
    const float* __restrict__ w_bbox, const float* __restrict__ b_bbox,
    const float* __restrict__ w_cls,  const float* __restrict__ b_cls,
    const float* __restrict__ w_reg,  const float* __restrict__ b_reg,
    const float* __restrict__ w_unc,  const float* __restrict__ b_unc,
    float* __restrict__ out, int n_rois)
{
    int idx = blockIdx.x * 256 + threadIdx.x;
    if (idx >= n_rois * 14) return;
    int n = idx / 14;
    int o = idx - n * 14;

    const float* w; float bb;
    if      (o < 8)  { w = w_bbox + o * D1;        bb = b_bbox[o]; }
    else if (o < 10) { w = w_cls  + (o - 8) * D1;  bb = b_cls[o - 8]; }
    else if (o < 12) { w = w_reg  + (o - 10) * D1; bb = b_reg[o - 10]; }
    else             { w = w_unc  + (o - 12) * D1; bb = b_unc[o - 12]; }

    const float* z = Z + (size_t)n * D1;
    float s = bb;
    for (int k = 0; k < D1; k += 4) {
        float4 zv = *(const float4*)(z + k);
        float4 wv = *(const float4*)(w + k);
        s = fmaf(zv.x, wv.x, s);
        s = fmaf(zv.y, wv.y, s);
        s = fmaf(zv.z, wv.z, s);
        s = fmaf(zv.w, wv.w, s);
    }

    int off;
    int clsOff = n_rois * 8;
    int regOff = n_rois * 8 + n_rois * 2;
    if      (o < 8)  off = n * 8 + o;
    else if (o < 10) off = clsOff + n * 2 + (o - 8);
    else if (o < 12) off = regOff + n * 4 + (o - 10) * 2;
    else             off = regOff + n * 4 + (o - 12) * 2 + 1;
    out[off] = s;
}

// ---------------------------------------------------------------------------
extern "C" void kernel_launch(void* const* d_in, const int* in_sizes, int n_in,
                              void* d_out, int out_size, void* d_ws, size_t ws_size,
                              hipStream_t stream)
{
    const float* f0   = (const float*)d_in[0];
    const float* f1   = (const float*)d_in[1];
    const float* f2   = (const float*)d_in[2];
    const float* f3   = (const float*)d_in[3];
    const float* rois = (const float*)d_in[4];
    const float* w1   = (const float*)d_in[5];
    const float* b1   = (const float*)d_in[6];
    const float* w2   = (const float*)d_in[7];
    const float* b2   = (const float*)d_in[8];
    const float* w_bbox = (const float*)d_in[9];
    const float* b_bbox = (const float*)d_in[10];
    const float* w_cls  = (const float*)d_in[11];
    const float* b_cls  = (const float*)d_in[12];
    const float* w_reg  = (const float*)d_in[13];
    const float* b_reg  = (const float*)d_in[14];
    const float* w_unc  = (const float*)d_in[15];
    const float* b_unc  = (const float*)d_in[16];
    float* out = (float*)d_out;

    const int n_rois = in_sizes[4] / 5;                  // 1000
    const int B      = in_sizes[0] / (C_CH * 128 * 128); // 4

    const size_t nh0B = (size_t)B * 16384 * C_CH * 2;
    const size_t nh1B = (size_t)B * 4096  * C_CH * 2;
    const size_t nh2B = (size_t)B * 1024  * C_CH * 2;
    const size_t nh3B = (size_t)B * 256   * C_CH * 2;
    const size_t nhAll = nh0B + nh1B + nh2B + nh3B;      // 33.4 MB
    const size_t poolB = (size_t)n_rois * PK * 2;        // 18.8 MB
    const size_t w1Bb  = (size_t)D1 * PK * 2;            // 14.45 MB
    const size_t w2Bb  = (size_t)D1 * D1 * 2;
    const size_t Yb    = (size_t)n_rois * D1 * 2;
    const size_t Zb    = (size_t)n_rois * D1 * 4;
    const size_t smallB = w2Bb + Yb + Zb;

    const size_t needX = nhAll + poolB + smallB;         // ~58.0 MB (proven rounds 4/5)

    char* ws = (char*)d_ws;

    if (ws_size >= needX) {
        // ---------------- Plan X: all NHWC levels resident ----------------
        // FC1: 64-tile ragged split-K=5 -> 960 blocks.
        //   alias (nhwc dead after gather): w1B 14.45 + P 5*3.07=15.36 = 29.8 <= 33.4 ✓
        // FC2: split-K=2, P2 aliases start of ws (w1B/P dead by then).
        const int SPLIT1 = 5;   // nkPer=30, splits: 30,30,30,30,27 (147 total)
        const int SPLIT2 = 2;   // K=768 -> 6+6 BK-iters

        ushort* nh0 = (ushort*)ws;
        ushort* nh1 = nh0 + nh0B/2;
        ushort* nh2 = nh1 + nh1B/2;
        ushort* nh3 = nh2 + nh2B/2;
        ushort* w1B = (ushort*)ws;                  // alias, used after gather
        float*  P   = (float*)(ws + w1Bb);          // alias, after gather
        float*  P2  = (float*)ws;                   // alias, after FC1 reduce
        ushort* pooledB = (ushort*)(ws + nhAll);
        ushort* w2B = (ushort*)(ws + nhAll + poolB);
        ushort* Y   = w2B + w2Bb/2;
        float*  Z   = (float*)((char*)Y + Yb);

        nchw_to_nhwc<<<dim3(680, B), 256, 0, stream>>>(f0, f1, f2, f3,
                                                       nh0, nh1, nh2, nh3);
        roi_gather<<<n_rois, 384, 0, stream>>>(nh0, nh1, nh2, nh3, rois, pooledB);

        cvt_bf16<<<((D1*PK/4) + 255)/256, 256, 0, stream>>>(w1, w1B, D1*PK/4);
        cvt_bf16<<<((D1*D1/4) + 255)/256, 256, 0, stream>>>(w2, w2B, D1*D1/4);

        // FC1: split-K partials + reduce -> Y bf16
        {
            int nkTotal = PK / 64;                          // 147
            int nkPer   = (nkTotal + SPLIT1 - 1) / SPLIT1;  // 30
            dim3 grid(D1/64, (n_rois + 63)/64, SPLIT1);
            mfma_gemm<2><<<grid, 256, 0, stream>>>(pooledB, w1B, nullptr, P,
                                                   n_rois, D1, PK, nkPer, nkTotal);
            int MN = n_rois * D1;
            reduce_relu_bf16<<<(MN/4 + 255)/256, 256, 0, stream>>>(P, b1, Y, MN, D1, SPLIT1);
        }
        // FC2: split-K partials + reduce -> Z fp32
        {
            int nkTotal = D1 / 64;                          // 12
            int nkPer   = nkTotal / SPLIT2;                 // 6
            dim3 grid(D1/64, (n_rois + 63)/64, SPLIT2);
            mfma_gemm<2><<<grid, 256, 0, stream>>>(Y, w2B, nullptr, P2,
                                                   n_rois, D1, D1, nkPer, nkTotal);
            int MN = n_rois * D1;
            reduce_relu_f32<<<(MN/4 + 255)/256, 256, 0, stream>>>(P2, b2, Z, MN, D1, SPLIT2);
        }
        heads_kernel<<<(n_rois*14 + 255)/256, 256, 0, stream>>>(
            Z, w_bbox, b_bbox, w_cls, b_cls, w_reg, b_reg, w_unc, b_unc, out, n_rois);
    } else {
        // ------- fallback: proven 39.1 MB layout (round-2 path) -------
        ushort* pooledB = (ushort*)ws;
        ushort* w1B = pooledB + poolB/2;
        ushort* w2B = w1B + w1Bb/2;
        ushort* Y   = w2B + w2Bb/2;
        float*  Z   = (float*)((char*)Y + Yb);

        cvt_bf16<<<((D1*PK/4) + 255)/256, 256, 0, stream>>>(w1, w1B, D1*PK/4);
        cvt_bf16<<<((D1*D1/4) + 255)/256, 256, 0, stream>>>(w2, w2B, D1*D1/4);
        {
            int total = n_rois * PK;
            roi_align_nchw<<<(total + 255)/256, 256, 0, stream>>>(
                f0, f1, f2, f3, rois, pooledB, n_rois);
        }
        {
            dim3 grid(D1/64, (n_rois + 63)/64);
            mfma_gemm<1><<<grid, 256, 0, stream>>>(pooledB, w1B, b1, Y,
                                                   n_rois, D1, PK, PK/64, PK/64);
        }
        {
            dim3 grid(D1/64, (n_rois + 63)/64);
            mfma_gemm<0><<<grid, 256, 0, stream>>>(Y, w2B, b2, Z,
                                                   n_rois, D1, D1, D1/64, D1/64);
        }
        heads_kernel<<<(n_rois*14 + 255)/256, 256, 0, stream>>>(
            Z, w_bbox, b_bbox, w_cls, b_cls, w_reg, b_reg, w_unc, b_unc, out, n_rois);
    }
}

// Round 7
// 246.171 us; speedup vs baseline: 1.4660x; 1.1147x over previous
//
#include <hip/hip_runtime.h>
#include <hip/hip_bf16.h>
#include <cstddef>
#include <cstdint>

typedef __attribute__((ext_vector_type(8))) short short8;
typedef __attribute__((ext_vector_type(16))) float float16;

#define C_CH 192
#define PK   9408      // C_CH * 49
#define D1   768

__device__ __forceinline__ ushort f2bf(float v) {
    return __builtin_bit_cast(unsigned short, __float2bfloat16(v));
}
__device__ __forceinline__ float bf2f(ushort u) {
    return __builtin_bit_cast(float, ((unsigned int)u) << 16);
}

// ---------------------------------------------------------------------------
// fp32 -> bf16 conversion for BOTH weight tensors in one launch
// ---------------------------------------------------------------------------
__global__ __launch_bounds__(256) void cvt_bf16_2(
    const float* __restrict__ in1, ushort* __restrict__ out1, int n4_1,
    const float* __restrict__ in2, ushort* __restrict__ out2, int n4_2)
{
    int i = blockIdx.x * 256 + threadIdx.x;
    const float* in; ushort* out;
    if (i < n4_1) { in = in1; out = out1; }
    else          { i -= n4_1; if (i >= n4_2) return; in = in2; out = out2; }
    float4 v = ((const float4*)in)[i];
    ushort4 o;
    o.x = f2bf(v.x); o.y = f2bf(v.y); o.z = f2bf(v.z); o.w = f2bf(v.w);
    ((ushort4*)out)[i] = o;
}

__global__ __launch_bounds__(256) void cvt_bf16(const float* __restrict__ in,
                                                ushort* __restrict__ out, int n4)
{
    int i = blockIdx.x * 256 + threadIdx.x;
    if (i >= n4) return;
    float4 v = ((const float4*)in)[i];
    ushort4 o;
    o.x = f2bf(v.x); o.y = f2bf(v.y); o.z = f2bf(v.z); o.w = f2bf(v.w);
    ((ushort4*)out)[i] = o;
}

// ---------------------------------------------------------------------------
// All 4 pyramid levels NCHW(fp32) -> NHWC(bf16), one launch.
// ---------------------------------------------------------------------------
__global__ __launch_bounds__(256) void nchw_to_nhwc(
    const float* __restrict__ f0, const float* __restrict__ f1,
    const float* __restrict__ f2, const float* __restrict__ f3,
    ushort* __restrict__ o0, ushort* __restrict__ o1,
    ushort* __restrict__ o2, ushort* __restrict__ o3)
{
    __shared__ float sm[C_CH][33];
    int t = blockIdx.x;
    int b = blockIdx.y;
    const float* in; ushort* out; int HW, hw0;
    if      (t < 512) { in = f0; out = o0; HW = 16384; hw0 = t * 32; }
    else if (t < 640) { in = f1; out = o1; HW = 4096;  hw0 = (t - 512) * 32; }
    else if (t < 672) { in = f2; out = o2; HW = 1024;  hw0 = (t - 640) * 32; }
    else              { in = f3; out = o3; HW = 256;   hw0 = (t - 672) * 32; }

    int tx = threadIdx.x & 31;
    int ty = threadIdx.x >> 5;    // 0..7

    const float* ip = in + (size_t)b * C_CH * HW + hw0;
    #pragma unroll
    for (int c = 0; c < C_CH; c += 8)
        sm[c + ty][tx] = ip[(size_t)(c + ty) * HW + tx];
    __syncthreads();

    ushort* op = out + ((size_t)b * HW + hw0) * C_CH;
    #pragma unroll
    for (int r0 = 0; r0 < 32; r0 += 8) {
        int r = r0 + ty;
        #pragma unroll
        for (int cc = 0; cc < 6; ++cc) {
            int c = cc * 32 + tx;
            op[(size_t)r * C_CH + c] = f2bf(sm[c][r]);
        }
    }
}

// ---------------------------------------------------------------------------
// RoIAlign gather from NHWC bf16: one block per RoI, 384 threads =
// 4 bin-groups x 96 threads; each thread covers 2 channels via dword load.
// Base pointer scalarized (readfirstlane) -> taps are saddr+voffset loads.
// ---------------------------------------------------------------------------
__global__ __launch_bounds__(384) void roi_gather(
    const ushort* __restrict__ n0p, const ushort* __restrict__ n1p,
    const ushort* __restrict__ n2p, const ushort* __restrict__ n3p,
    const float* __restrict__ rois, ushort* __restrict__ pooled)
{
    __shared__ int   s_offB[196][4];   // byte offsets
    __shared__ float s_w[196][4];
    __shared__ ushort s_out[PK];

    const int n   = blockIdx.x;
    const int tid = threadIdx.x;

    float by1 = rois[n*5+0], bx1 = rois[n*5+1];
    float by2 = rois[n*5+2], bx2 = rois[n*5+3];
    int   b   = (int)rois[n*5+4];

    float hh = by2 - by1, ww = bx2 - bx1;
    int lvl = (int)rintf(4.0f + log2f(sqrtf(hh * ww)));
    lvl = min(max(lvl, 0), 3);

    const ushort* fm; int H;
    if      (lvl == 0) { fm = n0p; H = 128; }
    else if (lvl == 1) { fm = n1p; H = 64;  }
    else if (lvl == 2) { fm = n2p; H = 32;  }
    else               { fm = n3p; H = 16;  }
    float Hf = (float)H;

    float y1p = by1 * Hf, x1p = bx1 * Hf;
    float y2p = by2 * Hf, x2p = bx2 * Hf;
    float bin_h = fmaxf(y2p - y1p, 1.0f) * (1.0f / 7.0f);
    float bin_w = fmaxf(x2p - x1p, 1.0f) * (1.0f / 7.0f);

    // scalarize base pointer (block-uniform): SGPR base + 32-bit voffset loads
    uintptr_t bp = (uintptr_t)(fm + (size_t)b * H * H * C_CH);
    unsigned int blo = __builtin_amdgcn_readfirstlane((unsigned int)bp);
    unsigned int bhi = __builtin_amdgcn_readfirstlane((unsigned int)(bp >> 32));
    const char* sbase = (const char*)((((uintptr_t)bhi) << 32) | blo);

    if (tid < 196) {
        int s  = tid;
        int sx = s & 1, sy = (s >> 1) & 1, ij = s >> 2;
        int i = ij / 7, j = ij - i * 7;

        float gy = (float)i + 0.25f + 0.5f * (float)sy;
        float y  = y1p + gy * bin_h;
        bool  vy = (y >= -1.0f) && (y <= Hf);
        float yc = fminf(fmaxf(y, 0.0f), Hf - 1.0f);
        int   y0 = (int)floorf(yc);
        float ly = yc - (float)y0;
        int   y1i = min(y0 + 1, H - 1);

        float gx = (float)j + 0.25f + 0.5f * (float)sx;
        float x  = x1p + gx * bin_w;
        bool  vx = (x >= -1.0f) && (x <= Hf);
        float xc = fminf(fmaxf(x, 0.0f), Hf - 1.0f);
        int   x0 = (int)floorf(xc);
        float lx = xc - (float)x0;
        int   x1i = min(x0 + 1, H - 1);

        float vm = (vy && vx) ? 0.25f : 0.0f;
        s_offB[s][0] = (y0  * H + x0 ) * (C_CH * 2);
        s_offB[s][1] = (y0  * H + x1i) * (C_CH * 2);
        s_offB[s][2] = (y1i * H + x0 ) * (C_CH * 2);
        s_offB[s][3] = (y1i * H + x1i) * (C_CH * 2);
        s_w[s][0] = (1.0f - ly) * (1.0f - lx) * vm;
        s_w[s][1] = (1.0f - ly) * lx * vm;
        s_w[s][2] = ly * (1.0f - lx) * vm;
        s_w[s][3] = ly * lx * vm;
    }
    __syncthreads();

    const int grp = tid / 96;            // 0..3 bin-group
    const int ci  = tid - grp * 96;      // channel-pair index
    const int c   = ci * 2;              // channels c, c+1
    const int c4  = ci * 4;              // byte offset of channel pair
    const int bin_lo = grp * 13;
    const int bin_hi = min(bin_lo + 13, 49);

    for (int bin = bin_lo; bin < bin_hi; ++bin) {
        float a0 = 0.0f, a1 = 0.0f;
        #pragma unroll
        for (int sub = 0; sub < 4; ++sub) {
            int s = bin * 4 + sub;
            #pragma unroll
            for (int tp = 0; tp < 4; ++tp) {
                int ob  = s_offB[s][tp];
                float w = s_w[s][tp];
                unsigned int u = *(const unsigned int*)(sbase + (ob + c4));
                float lo = __builtin_bit_cast(float, u << 16);
                float hi = __builtin_bit_cast(float, u & 0xffff0000u);
                a0 = fmaf(lo, w, a0);
                a1 = fmaf(hi, w, a1);
            }
        }
        s_out[(c + 0) * 49 + bin] = f2bf(a0);
        s_out[(c + 1) * 49 + bin] = f2bf(a1);
    }
    __syncthreads();

    unsigned int* po = (unsigned int*)(pooled + (size_t)n * PK);
    const unsigned int* so = (const unsigned int*)s_out;
    for (int idx = tid; idx < PK / 2; idx += 384) po[idx] = so[idx];
}

// ---------------------------------------------------------------------------
// RoIAlign from NCHW fp32 (fallback path, proven): 1 thread / output element
// ---------------------------------------------------------------------------
__global__ __launch_bounds__(256) void roi_align_nchw(
    const float* __restrict__ f0, const float* __restrict__ f1,
    const float* __restrict__ f2, const float* __restrict__ f3,
    const float* __restrict__ rois, ushort* __restrict__ pooled, int n_rois)
{
    int idx = blockIdx.x * 256 + threadIdx.x;
    if (idx >= n_rois * PK) return;
    int n  = idx / PK;
    int r  = idx - n * PK;
    int c  = r / 49;
    int ij = r - c * 49;
    int i  = ij / 7;
    int j  = ij - i * 7;

    float by1 = rois[n*5+0], bx1 = rois[n*5+1];
    float by2 = rois[n*5+2], bx2 = rois[n*5+3];
    int   b   = (int)rois[n*5+4];

    float hh = by2 - by1, ww = bx2 - bx1;
    int lvl = (int)rintf(4.0f + log2f(sqrtf(hh * ww)));
    lvl = min(max(lvl, 0), 3);

    const float* fmap; int H;
    if      (lvl == 0) { fmap = f0; H = 128; }
    else if (lvl == 1) { fmap = f1; H = 64;  }
    else if (lvl == 2) { fmap = f2; H = 32;  }
    else               { fmap = f3; H = 16;  }
    float Hf = (float)H;

    float y1p = by1 * Hf, x1p = bx1 * Hf;
    float bin_h = fmaxf(by2 * Hf - y1p, 1.0f) * (1.0f / 7.0f);
    float bin_w = fmaxf(bx2 * Hf - x1p, 1.0f) * (1.0f / 7.0f);

    const float* base = fmap + ((size_t)b * C_CH + c) * (size_t)(H * H);

    float acc = 0.0f;
    #pragma unroll
    for (int sy = 0; sy < 2; ++sy) {
        float y  = y1p + ((float)i + 0.25f + 0.5f * (float)sy) * bin_h;
        bool  vy = (y >= -1.0f) && (y <= Hf);
        float yc = fminf(fmaxf(y, 0.0f), Hf - 1.0f);
        int   y0 = (int)floorf(yc);
        float ly = yc - (float)y0;
        int   y1i = min(y0 + 1, H - 1);
        #pragma unroll
        for (int sx = 0; sx < 2; ++sx) {
            float x  = x1p + ((float)j + 0.25f + 0.5f * (float)sx) * bin_w;
            bool  vx = (x >= -1.0f) && (x <= Hf);
            float xc = fminf(fmaxf(x, 0.0f), Hf - 1.0f);
            int   x0 = (int)floorf(xc);
            float lx = xc - (float)x0;
            int   x1i = min(x0 + 1, H - 1);
            if (vy && vx) {
                float v = base[y0 * H + x0 ] * (1.0f - ly) * (1.0f - lx)
                        + base[y0 * H + x1i] * (1.0f - ly) * lx
                        + base[y1i * H + x0 ] * ly * (1.0f - lx)
                        + base[y1i * H + x1i] * ly * lx;
                acc += v;
            }
        }
    }
    pooled[idx] = f2bf(acc * 0.25f);
}

// ---------------------------------------------------------------------------
// bf16 MFMA GEMM, 64x64 tile, BK=64, double-buffered LDS, XOR swizzle.
// MODE 0: fp32 out bias+relu. MODE 1: bf16 out bias+relu.
// MODE 2: fp32 partial, ragged split-K.
// ---------------------------------------------------------------------------
template<int MODE>
__global__ __launch_bounds__(256) void mfma_gemm(
    const ushort* __restrict__ A, const ushort* __restrict__ W,
    const float* __restrict__ bias, void* __restrict__ outp,
    int M, int N, int K, int nkPer, int nkTotal)
{
    __shared__ char ldsA[2][8192];
    __shared__ char ldsB[2][8192];

    const int t    = threadIdx.x;
    const int lane = t & 63;
    const int wave = t >> 6;
    const int wm = wave >> 1, wn = wave & 1;

    const int m0 = blockIdx.y * 64;
    const int n0 = blockIdx.x * 64;
    const int kb = (MODE == 2) ? blockIdx.z * nkPer : 0;
    const int nk = (MODE == 2) ? min(nkPer, nkTotal - kb) : nkPer;

    const int ks   = t & 3;
    const int mrow = t >> 2;
    const int g    = mrow >> 5;
    const int rw   = mrow & 31;
    const int lof0 = ks*2048 + g*1024 + ((     rw) ^ (ks<<2))*16;
    const int lof1 = ks*2048 + g*1024 + ((32 + rw) ^ (ks<<2))*16;

    const int arow = min(m0 + mrow, M-1);
    const int brow = n0 + mrow;
    const ushort* ap = A + (size_t)arow * K + (size_t)kb * 64 + ks*16;
    const ushort* bp = W + (size_t)brow * K + (size_t)kb * 64 + ks*16;

    float4 ra0, ra1, rb0, rb1;
    float4 qa0, qa1, qb0, qb1;

    ra0 = ((const float4*)ap)[0]; ra1 = ((const float4*)ap)[1];
    rb0 = ((const float4*)bp)[0]; rb1 = ((const float4*)bp)[1];
    *(float4*)&ldsA[0][lof0] = ra0; *(float4*)&ldsA[0][lof1] = ra1;
    *(float4*)&ldsB[0][lof0] = rb0; *(float4*)&ldsB[0][lof1] = rb1;
    {
        int k1 = min(1, nk - 1);
        const ushort* ap1 = ap + (size_t)k1 * 64;
        const ushort* bp1 = bp + (size_t)k1 * 64;
        ra0 = ((const float4*)ap1)[0]; ra1 = ((const float4*)ap1)[1];
        rb0 = ((const float4*)bp1)[0]; rb1 = ((const float4*)bp1)[1];
    }
    __syncthreads();

    float16 acc = {};

    for (int kt = 0; kt < nk; ++kt) {
        {
            int k2 = min(kt + 2, nk - 1);
            const ushort* ap2 = ap + (size_t)k2 * 64;
            const ushort* bp2 = bp + (size_t)k2 * 64;
            qa0 = ((const float4*)ap2)[0]; qa1 = ((const float4*)ap2)[1];
            qb0 = ((const float4*)bp2)[0]; qb1 = ((const float4*)bp2)[1];
        }
        if (kt + 1 < nk) {
            char* dA = ldsA[(kt+1)&1]; char* dB = ldsB[(kt+1)&1];
            *(float4*)&dA[lof0] = ra0; *(float4*)&dA[lof1] = ra1;
            *(float4*)&dB[lof0] = rb0; *(float4*)&dB[lof1] = rb1;
        }
        const char* sA = ldsA[kt&1]; const char* sB = ldsB[kt&1];
        #pragma unroll
        for (int s = 0; s < 4; ++s) {
            int ro = s*2048 + (lane ^ (s<<2))*16;
            short8 af = *(const short8*)&sA[wm*1024 + ro];
            short8 bf = *(const short8*)&sB[wn*1024 + ro];
            acc = __builtin_amdgcn_mfma_f32_32x32x16_bf16(af, bf, acc, 0, 0, 0);
        }
        __syncthreads();
        ra0 = qa0; ra1 = qa1; rb0 = qb0; rb1 = qb1;
    }

    const int col   = lane & 31;
    const int rbase = 4 * (lane >> 5);
    const int nG    = n0 + wn*32 + col;

    if (MODE == 2) {
        float* O = (float*)outp + (size_t)blockIdx.z * M * N;
        #pragma unroll
        for (int r = 0; r < 16; ++r) {
            int row = (r & 3) + 8*(r >> 2) + rbase;
            int mG  = m0 + wm*32 + row;
            if (mG < M) O[(size_t)mG * N + nG] = acc[r];
        }
    } else if (MODE == 1) {
        const float bv = bias[nG];
        ushort* O = (ushort*)outp;
        #pragma unroll
        for (int r = 0; r < 16; ++r) {
            int row = (r & 3) + 8*(r >> 2) + rbase;
            int mG  = m0 + wm*32 + row;
            if (mG < M) O[(size_t)mG * N + nG] = f2bf(fmaxf(acc[r] + bv, 0.0f));
        }
    } else {
        const float bv = bias[nG];
        float* O = (float*)outp;
        #pragma unroll
        for (int r = 0; r < 16; ++r) {
            int row = (r & 3) + 8*(r >> 2) + rbase;
            int mG  = m0 + wm*32 + row;
            if (mG < M) O[(size_t)mG * N + nG] = fmaxf(acc[r] + bv, 0.0f);
        }
    }
}

// ---------------------------------------------------------------------------
// FC1 split-K reduce -> bf16 Y
// ---------------------------------------------------------------------------
__global__ __launch_bounds__(256) void reduce_relu_bf16(
    const float* __restrict__ P, const float* __restrict__ bias,
    ushort* __restrict__ Y, int MN, int N, int S)
{
    int idx = blockIdx.x * 256 + threadIdx.x;
    if (idx >= MN / 4) return;
    float4 s = ((const float4*)P)[idx];
    for (int k = 1; k < S; ++k) {
        float4 p = ((const float4*)(P + (size_t)k * MN))[idx];
        s.x += p.x; s.y += p.y; s.z += p.z; s.w += p.w;
    }
    int n4 = idx % (N / 4);
    float4 bv = ((const float4*)bias)[n4];
    ushort4 o;
    o.x = f2bf(fmaxf(s.x + bv.x, 0.0f));
    o.y = f2bf(fmaxf(s.y + bv.y, 0.0f));
    o.z = f2bf(fmaxf(s.z + bv.z, 0.0f));
    o.w = f2bf(fmaxf(s.w + bv.w, 0.0f));
    ((ushort4*)Y)[idx] = o;
}

// ---------------------------------------------------------------------------
// Fused FC2-reduce + relu + heads. One block per RoI (256 threads).
// P2: [S][M][768] fp32 partials of FC2. Computes z = relu(b2 + sum_s P2),
// then 14 K=768 dots, scattered to d_out.
// ---------------------------------------------------------------------------
__global__ __launch_bounds__(256) void reduce_heads(
    const float* __restrict__ P2, const float* __restrict__ b2, int S, int MN,
    const float* __restrict__ w_bbox, const float* __restrict__ b_bbox,
    const float* __restrict__ w_cls,  const float* __restrict__ b_cls,
    const float* __restrict__ w_reg,  const float* __restrict__ b_reg,
    const float* __restrict__ w_unc,  const float* __restrict__ b_unc,
    float* __restrict__ out, int n_rois)
{
    __shared__ float zrow[D1];
    const int m   = blockIdx.x;
    const int tid = threadIdx.x;

    const float* Pm = P2 + (size_t)m * D1;
    #pragma unroll
    for (int r = 0; r < 3; ++r) {               // 768 = 3 * 256
        int k = r * 256 + tid;
        float v = Pm[k];
        for (int s = 1; s < S; ++s) v += Pm[(size_t)s * MN + k];
        zrow[k] = fmaxf(v + b2[k], 0.0f);
    }
    __syncthreads();

    const int wave = tid >> 6;
    const int lane = tid & 63;
    for (int o = wave; o < 14; o += 4) {
        const float* w; float bb;
        if      (o < 8)  { w = w_bbox + o * D1;        bb = b_bbox[o]; }
        else if (o < 10) { w = w_cls  + (o - 8) * D1;  bb = b_cls[o - 8]; }
        else if (o < 12) { w = w_reg  + (o - 10) * D1; bb = b_reg[o - 10]; }
        else             { w = w_unc  + (o - 12) * D1; bb = b_unc[o - 12]; }
        float p = 0.0f;
        #pragma unroll
        for (int r = 0; r < 12; ++r) {          // 768 = 12 * 64
            int k = r * 64 + lane;
            p = fmaf(zrow[k], w[k], p);
        }
        #pragma unroll
        for (int d = 32; d >= 1; d >>= 1) p += __shfl_down(p, d, 64);
        if (lane == 0) {
            int off;
            int clsOff = n_rois * 8;
            int regOff = n_rois * 10;
            if      (o < 8)  off = m * 8 + o;
            else if (o < 10) off = clsOff + m * 2 + (o - 8);
            else if (o < 12) off = regOff + m * 4 + (o - 10) * 2;
            else             off = regOff + m * 4 + (o - 12) * 2 + 1;
            out[off] = p + bb;
        }
    }
}

// ---------------------------------------------------------------------------
// Heads (fallback path)
// ---------------------------------------------------------------------------
__global__ __launch_bounds__(256) void heads_kernel(
    const float* __restrict__ Z,
    const float* __restrict__ w_bbox, const float* __restrict__ b_bbox,
    const float* __restrict__ w_cls,  const float* __restrict__ b_cls,
    const float* __restrict__ w_reg,  const float* __restrict__ b_reg,
    const float* __restrict__ w_unc,  const float* __restrict__ b_unc,
    float* __restrict__ out, int n_rois)
{
    int idx = blockIdx.x * 256 + threadIdx.x;
    if (idx >= n_rois * 14) return;
    int n = idx / 14;
    int o = idx - n * 14;

    const float* w; float bb;
    if      (o < 8)  { w = w_bbox + o * D1;        bb = b_bbox[o]; }
    else if (o < 10) { w = w_cls  + (o - 8) * D1;  bb = b_cls[o - 8]; }
    else if (o < 12) { w = w_reg  + (o - 10) * D1; bb = b_reg[o - 10]; }
    else             { w = w_unc  + (o - 12) * D1; bb = b_unc[o - 12]; }

    const float* z = Z + (size_t)n * D1;
    float s = bb;
    for (int k = 0; k < D1; k += 4) {
        float4 zv = *(const float4*)(z + k);
        float4 wv = *(const float4*)(w + k);
        s = fmaf(zv.x, wv.x, s);
        s = fmaf(zv.y, wv.y, s);
        s = fmaf(zv.z, wv.z, s);
        s = fmaf(zv.w, wv.w, s);
    }

    int off;
    int clsOff = n_rois * 8;
    int regOff = n_rois * 10;
    if      (o < 8)  off = n * 8 + o;
    else if (o < 10) off = clsOff + n * 2 + (o - 8);
    else if (o < 12) off = regOff + n * 4 + (o - 10) * 2;
    else             off = regOff + n * 4 + (o - 12) * 2 + 1;
    out[off] = s;
}

// ---------------------------------------------------------------------------
extern "C" void kernel_launch(void* const* d_in, const int* in_sizes, int n_in,
                              void* d_out, int out_size, void* d_ws, size_t ws_size,
                              hipStream_t stream)
{
    const float* f0   = (const float*)d_in[0];
    const float* f1   = (const float*)d_in[1];
    const float* f2   = (const float*)d_in[2];
    const float* f3   = (const float*)d_in[3];
    const float* rois = (const float*)d_in[4];
    const float* w1   = (const float*)d_in[5];
    const float* b1   = (const float*)d_in[6];
    const float* w2   = (const float*)d_in[7];
    const float* b2   = (const float*)d_in[8];
    const float* w_bbox = (const float*)d_in[9];
    const float* b_bbox = (const float*)d_in[10];
    const float* w_cls  = (const float*)d_in[11];
    const float* b_cls  = (const float*)d_in[12];
    const float* w_reg  = (const float*)d_in[13];
    const float* b_reg  = (const float*)d_in[14];
    const float* w_unc  = (const float*)d_in[15];
    const float* b_unc  = (const float*)d_in[16];
    float* out = (float*)d_out;

    const int n_rois = in_sizes[4] / 5;                  // 1000
    const int B      = in_sizes[0] / (C_CH * 128 * 128); // 4

    const size_t nh0B = (size_t)B * 16384 * C_CH * 2;
    const size_t nh1B = (size_t)B * 4096  * C_CH * 2;
    const size_t nh2B = (size_t)B * 1024  * C_CH * 2;
    const size_t nh3B = (size_t)B * 256   * C_CH * 2;
    const size_t nhAll = nh0B + nh1B + nh2B + nh3B;      // 33.4 MB
    const size_t poolB = (size_t)n_rois * PK * 2;        // 18.8 MB
    const size_t w1Bb  = (size_t)D1 * PK * 2;            // 14.45 MB
    const size_t w2Bb  = (size_t)D1 * D1 * 2;
    const size_t Yb    = (size_t)n_rois * D1 * 2;
    const size_t Zb    = (size_t)n_rois * D1 * 4;
    const size_t smallB = w2Bb + Yb + Zb;

    const size_t needX = nhAll + poolB + smallB;         // ~58.0 MB (proven)

    char* ws = (char*)d_ws;

    if (ws_size >= needX) {
        // ---------------- Plan X ----------------
        const int SPLIT1 = 5;   // FC1: nkPer=30 -> 30,30,30,30,27 (147)
        const int SPLIT2 = 2;   // FC2: 6+6

        ushort* nh0 = (ushort*)ws;
        ushort* nh1 = nh0 + nh0B/2;
        ushort* nh2 = nh1 + nh1B/2;
        ushort* nh3 = nh2 + nh2B/2;
        ushort* w1B = (ushort*)ws;                  // alias after gather
        float*  P   = (float*)(ws + w1Bb);          // alias after gather
        float*  P2  = (float*)ws;                   // alias after FC1 gemm
        ushort* pooledB = (ushort*)(ws + nhAll);
        ushort* w2B = (ushort*)(ws + nhAll + poolB);
        ushort* Y   = w2B + w2Bb/2;

        nchw_to_nhwc<<<dim3(680, B), 256, 0, stream>>>(f0, f1, f2, f3,
                                                       nh0, nh1, nh2, nh3);
        roi_gather<<<n_rois, 384, 0, stream>>>(nh0, nh1, nh2, nh3, rois, pooledB);

        {
            int n41 = D1*PK/4, n42 = D1*D1/4;
            cvt_bf16_2<<<(n41 + n42 + 255)/256, 256, 0, stream>>>(
                w1, w1B, n41, w2, w2B, n42);
        }
        // FC1: split-K partials + reduce -> Y bf16
        {
            int nkTotal = PK / 64;                          // 147
            int nkPer   = (nkTotal + SPLIT1 - 1) / SPLIT1;  // 30
            dim3 grid(D1/64, (n_rois + 63)/64, SPLIT1);
            mfma_gemm<2><<<grid, 256, 0, stream>>>(pooledB, w1B, nullptr, P,
                                                   n_rois, D1, PK, nkPer, nkTotal);
            int MN = n_rois * D1;
            reduce_relu_bf16<<<(MN/4 + 255)/256, 256, 0, stream>>>(P, b1, Y, MN, D1, SPLIT1);
        }
        // FC2 partials -> fused reduce+relu+heads
        {
            int nkTotal = D1 / 64;                          // 12
            int nkPer   = nkTotal / SPLIT2;                 // 6
            dim3 grid(D1/64, (n_rois + 63)/64, SPLIT2);
            mfma_gemm<2><<<grid, 256, 0, stream>>>(Y, w2B, nullptr, P2,
                                                   n_rois, D1, D1, nkPer, nkTotal);
            int MN = n_rois * D1;
            reduce_heads<<<n_rois, 256, 0, stream>>>(P2, b2, SPLIT2, MN,
                w_bbox, b_bbox, w_cls, b_cls, w_reg, b_reg, w_unc, b_unc, out, n_rois);
        }
    } else {
        // ------- fallback: proven 39.1 MB layout -------
        ushort* pooledB = (ushort*)ws;
        ushort* w1B = pooledB + poolB/2;
        ushort* w2B = w1B + w1Bb/2;
        ushort* Y   = w2B + w2Bb/2;
        float*  Z   = (float*)((char*)Y + Yb);

        cvt_bf16<<<((D1*PK/4) + 255)/256, 256, 0, stream>>>(w1, w1B, D1*PK/4);
        cvt_bf16<<<((D1*D1/4) + 255)/256, 256, 0, stream>>>(w2, w2B, D1*D1/4);
        {
            int total = n_rois * PK;
            roi_align_nchw<<<(total + 255)/256, 256, 0, stream>>>(
                f0, f1, f2, f3, rois, pooledB, n_rois);
        }
        {
            dim3 grid(D1/64, (n_rois + 63)/64);
            mfma_gemm<1><<<grid, 256, 0, stream>>>(pooledB, w1B, b1, Y,
                                                   n_rois, D1, PK, PK/64, PK/64);
        }
        {
            dim3 grid(D1/64, (n_rois + 63)/64);
            mfma_gemm<0><<<grid, 256, 0, stream>>>(Y, w2B, b2, Z,
                                                   n_rois, D1, D1, D1/64, D1/64);
        }
        heads_kernel<<<(n_rois*14 + 255)/256, 256, 0, stream>>>(
            Z, w_bbox, b_bbox, w_cls, b_cls, w_reg, b_reg, w_unc, b_unc, out, n_rois);
    }
}